// Round 2
// baseline (225.808 us; speedup 1.0000x reference)
//
#include <hip/hip_runtime.h>
#include <math.h>

#define CHW 32768        // C*H*W = 8*64*64
#define NELEM 1048576    // B*C*H*W
#define NBLOCKS 2048
#define CHUNKS_PER_BLOCK 8

__global__ void init_sldj_kernel(const float* __restrict__ sldj,
                                 float* __restrict__ out_sldj, int B) {
    int i = blockIdx.x * blockDim.x + threadIdx.x;
    if (i < B) out_sldj[i] = sldj[i];
}

// 4 lanes per element, 4 mixture components per lane.
// Lane gid reads float4 #gid of pi/mu/s -> perfectly coalesced 16B/lane.
__global__ __launch_bounds__(256, 8) void coupling_kernel(
    const float* __restrict__ x_change, const float* __restrict__ x_id,
    const float* __restrict__ a, const float* __restrict__ b,
    const float4* __restrict__ pi4, const float4* __restrict__ mu4,
    const float4* __restrict__ s4, float* __restrict__ out) {
    const int t = threadIdx.x;
    const int kq = t & 3;          // which quad of components this lane owns
    const int grp = t >> 2;        // element within chunk (0..63)
    float ldj_acc = 0.0f;

    for (int it = 0; it < CHUNKS_PER_BLOCK; ++it) {
        const int chunk = blockIdx.x * CHUNKS_PER_BLOCK + it;
        const int e = chunk * 64 + grp;                 // element index
        const size_t fi = (size_t)e * 4 + kq;           // float4 index (== global lane id)

        const float4 p = pi4[fi];
        const float4 m = mu4[fi];
        const float4 sv = s4[fi];
        const float x = x_change[e];

        // ---- max over this element's 16 pi values ----
        float pmax = fmaxf(fmaxf(p.x, p.y), fmaxf(p.z, p.w));
        pmax = fmaxf(pmax, __shfl_xor(pmax, 1));
        pmax = fmaxf(pmax, __shfl_xor(pmax, 2));

        // ---- per-component fused terms ----
        // w = e^{p-pmax};  g = sigmoid(z);  cdf += w*g;  pdf += w*e^{-s}*g*(1-g)
        float psum = 0.0f, cdf = 0.0f, pdf = 0.0f;
        {
            const float pk[4] = {p.x, p.y, p.z, p.w};
            const float mk[4] = {m.x, m.y, m.z, m.w};
            const float sk[4] = {sv.x, sv.y, sv.z, sv.w};
#pragma unroll
            for (int j = 0; j < 4; ++j) {
                const float w = __expf(pk[j] - pmax);
                const float ez = __expf(-sk[j]);
                const float z = (x - mk[j]) * ez;
                const float g = __builtin_amdgcn_rcpf(1.0f + __expf(-z));
                psum += w;
                cdf += w * g;
                pdf += w * ez * g * (1.0f - g);
            }
        }
        // ---- reduce the three sums over the 4-lane group ----
        psum += __shfl_xor(psum, 1); psum += __shfl_xor(psum, 2);
        cdf  += __shfl_xor(cdf, 1);  cdf  += __shfl_xor(cdf, 2);
        pdf  += __shfl_xor(pdf, 1);  pdf  += __shfl_xor(pdf, 2);

        if (kq == 0) {
            const float lpsum = __logf(psum);
            const float log_cdf = __logf(cdf) - lpsum;        // <= 0
            const float logistic_ldj = __logf(pdf) - lpsum;
            float omu = -expm1f(log_cdf);                      // 1 - u, accurate
            omu = fmaxf(omu, 1e-38f);
            const float l1mu = __logf(omu);
            const float av = a[e];
            const float bv = b[e];
            out[e] = (log_cdf - l1mu + bv) * __expf(av);
            ldj_acc += logistic_ldj - log_cdf - l1mu + av;
        } else if (kq == 1) {
            out[(size_t)NELEM + e] = x_id[e];                  // identity passthrough
        }
    }

    // ---- block reduction of ldj_acc (non-zero only on kq==0 lanes) ----
    float v = ldj_acc;
#pragma unroll
    for (int off = 32; off > 0; off >>= 1) v += __shfl_down(v, off);
    __shared__ float ws[4];
    const int wid = threadIdx.x >> 6;
    if ((threadIdx.x & 63) == 0) ws[wid] = v;
    __syncthreads();
    if (threadIdx.x == 0) {
        const float tot = ws[0] + ws[1] + ws[2] + ws[3];
        const int batch = blockIdx.x >> 6;   // 64 blocks per batch (512 elems/block, 32768/batch)
        atomicAdd(out + 2 * (size_t)NELEM + batch, tot);
    }
}

extern "C" void kernel_launch(void* const* d_in, const int* in_sizes, int n_in,
                              void* d_out, int out_size, void* d_ws, size_t ws_size,
                              hipStream_t stream) {
    const float* x_change = (const float*)d_in[0];
    const float* x_id     = (const float*)d_in[1];
    const float* sldj     = (const float*)d_in[2];
    const float* a        = (const float*)d_in[3];
    const float* b        = (const float*)d_in[4];
    const float4* pi      = (const float4*)d_in[5];
    const float4* mu      = (const float4*)d_in[6];
    const float4* s       = (const float4*)d_in[7];
    float* out = (float*)d_out;

    const int B = in_sizes[2];

    // Seed sldj output region (harness poisons d_out), then main kernel
    // atomically accumulates into it (stream-ordered).
    init_sldj_kernel<<<1, 64, 0, stream>>>(sldj, out + 2 * (size_t)NELEM, B);

    coupling_kernel<<<NBLOCKS, 256, 0, stream>>>(x_change, x_id, a, b, pi, mu, s, out);
}

// Round 3
// 222.660 us; speedup vs baseline: 1.0141x; 1.0141x over previous
//
#include <hip/hip_runtime.h>
#include <math.h>

#define KCOMP 16
#define CHW 32768        // C*H*W = 8*64*64
#define LOG2E 1.44269504088896340736f
#define LN2   0.69314718055994530942f

__global__ void init_sldj_kernel(const float* __restrict__ sldj,
                                 float* __restrict__ out_sldj, int B) {
    int i = blockIdx.x * blockDim.x + threadIdx.x;
    if (i < B) out_sldj[i] = sldj[i];
}

// One thread per element; all transcendentals forced to native v_exp_f32 /
// v_log_f32 / v_rcp_f32 via amdgcn builtins (base-2 algebra).
__global__ __launch_bounds__(256) void coupling_kernel(
    const float* __restrict__ x_change, const float* __restrict__ x_id,
    const float* __restrict__ a, const float* __restrict__ b,
    const float* __restrict__ pi, const float* __restrict__ mu,
    const float* __restrict__ s, float* __restrict__ out, int N) {
    const int i = blockIdx.x * blockDim.x + threadIdx.x;
    float ldj_term = 0.0f;
    if (i < N) {
        const float x = x_change[i];
        const size_t base = (size_t)i * KCOMP;

        // ---- load pi (16 floats) ----
        float p[KCOMP];
        {
            const float4* pv = (const float4*)(pi + base);
#pragma unroll
            for (int c = 0; c < 4; ++c) {
                float4 t0 = pv[c];
                p[4 * c + 0] = t0.x; p[4 * c + 1] = t0.y;
                p[4 * c + 2] = t0.z; p[4 * c + 3] = t0.w;
            }
        }
        float pmax = p[0];
#pragma unroll
        for (int k = 1; k < KCOMP; ++k) pmax = fmaxf(pmax, p[k]);

        // w_k = 2^((p_k - pmax)*log2e)
        float w[KCOMP];
        float psum = 0.0f;
#pragma unroll
        for (int k = 0; k < KCOMP; ++k) {
            w[k] = __builtin_amdgcn_exp2f((p[k] - pmax) * LOG2E);
            psum += w[k];
        }

        // ---- load mu, s and accumulate cdf / (1-cdf) / pdf sums ----
        float m[KCOMP], sv[KCOMP];
        {
            const float4* mv = (const float4*)(mu + base);
            const float4* svv = (const float4*)(s + base);
#pragma unroll
            for (int c = 0; c < 4; ++c) {
                float4 t1 = mv[c];
                m[4 * c + 0] = t1.x; m[4 * c + 1] = t1.y;
                m[4 * c + 2] = t1.z; m[4 * c + 3] = t1.w;
                float4 t2 = svv[c];
                sv[4 * c + 0] = t2.x; sv[4 * c + 1] = t2.y;
                sv[4 * c + 2] = t2.z; sv[4 * c + 3] = t2.w;
            }
        }

        float cdf = 0.0f, omu = 0.0f, pdf = 0.0f;
#pragma unroll
        for (int k = 0; k < KCOMP; ++k) {
            const float ez = __builtin_amdgcn_exp2f(-sv[k] * LOG2E);  // e^{-s}
            const float z = (x - m[k]) * ez;
            const float enz = __builtin_amdgcn_exp2f(-z * LOG2E);     // e^{-z}
            const float g = __builtin_amdgcn_rcpf(1.0f + enz);        // sigmoid(z)
            const float wg = w[k] * g;
            cdf += wg;                  // Σ w·g
            omu += wg * enz;            // Σ w·(1-g)   [1-g = g·e^{-z}]
            pdf += w[k] * ez * g * g * enz;  // Σ w·e^{-s}·g·(1-g)
        }

        // ---- logs (base 2 -> natural) ----
        const float l2psum = __builtin_amdgcn_logf(psum);
        const float l2cdf  = __builtin_amdgcn_logf(cdf);
        const float l2omu  = __builtin_amdgcn_logf(fmaxf(omu, 1e-38f));
        const float l2pdf  = __builtin_amdgcn_logf(fmaxf(pdf, 1e-38f));

        const float av = a[i];
        const float bv = b[i];
        // out = (log_cdf - log(1-u) + b) * e^a ; log_cdf - log(1-u) = (l2cdf - l2omu)*ln2
        const float outv = (l2cdf - l2omu) * LN2;
        out[i] = (outv + bv) * __builtin_amdgcn_exp2f(av * LOG2E);
        out[(size_t)N + i] = x_id[i];
        // ldj = log_pdf - log_cdf - log(1-u) + a
        ldj_term = (l2pdf + l2psum - l2cdf - l2omu) * LN2 + av;
    }

    // ---- block reduction; each block (256 elems) lies within one batch ----
    float v = ldj_term;
#pragma unroll
    for (int off = 32; off > 0; off >>= 1) v += __shfl_down(v, off);
    __shared__ float ws[4];
    const int wid = threadIdx.x >> 6;
    if ((threadIdx.x & 63) == 0) ws[wid] = v;
    __syncthreads();
    if (threadIdx.x == 0) {
        const float tot = ws[0] + ws[1] + ws[2] + ws[3];
        const int batch = (blockIdx.x * blockDim.x) / CHW;
        atomicAdd(out + 2 * (size_t)N + batch, tot);
    }
}

extern "C" void kernel_launch(void* const* d_in, const int* in_sizes, int n_in,
                              void* d_out, int out_size, void* d_ws, size_t ws_size,
                              hipStream_t stream) {
    const float* x_change = (const float*)d_in[0];
    const float* x_id     = (const float*)d_in[1];
    const float* sldj     = (const float*)d_in[2];
    const float* a        = (const float*)d_in[3];
    const float* b        = (const float*)d_in[4];
    const float* pi       = (const float*)d_in[5];
    const float* mu       = (const float*)d_in[6];
    const float* s        = (const float*)d_in[7];
    float* out = (float*)d_out;

    const int N = in_sizes[0];   // B*C*H*W
    const int B = in_sizes[2];

    init_sldj_kernel<<<1, 64, 0, stream>>>(sldj, out + 2 * (size_t)N, B);

    const int block = 256;
    const int grid = (N + block - 1) / block;
    coupling_kernel<<<grid, block, 0, stream>>>(x_change, x_id, a, b, pi, mu, s, out, N);
}